// Round 1
// baseline (5930.387 us; speedup 1.0000x reference)
//
#include <hip/hip_runtime.h>
#include <hip/hip_bf16.h>
#include <math.h>

// ---------------------------------------------------------------------------
// DecoderTARDIS forward, fp32, JAX-threefry-exact gumbel reproduction.
// Set TF_PARTITIONABLE=0 if validation fails with O(1) error (legacy counter
// layout of jax_threefry_partitionable=False).
// ---------------------------------------------------------------------------
#define TF_PARTITIONABLE 1

static constexpr int LL    = 32;
static constexpr int BB    = 128;
static constexpr int IDIM  = 512;
static constexpr int HDIM  = 1024;
static constexpr int NSLOT = 512;
static constexpr int AA    = 128;
static constexpr int CC    = 128;
static constexpr int AC    = 256;
// packed weight columns: [0,1024)=h2c/i2c, [1024,1280)=h2w/i2w,
// [1280,1283)=gates, [1283,1285)=ab, 1285=tau, pad to 1312
static constexpr int WCOLS   = 1312;
static constexpr int COL_W0  = 1024;
static constexpr int COL_G0  = 1280;
static constexpr int COL_AB0 = 1283;
static constexpr int COL_TAU = 1285;

// ------------------------------ threefry -----------------------------------
__device__ __forceinline__ uint32_t rotl32(uint32_t x, uint32_t r) {
  return (x << r) | (x >> (32u - r));
}

__device__ __forceinline__ void threefry2x32(uint32_t k0, uint32_t k1,
                                             uint32_t x0, uint32_t x1,
                                             uint32_t& o0, uint32_t& o1) {
  uint32_t ks0 = k0, ks1 = k1, ks2 = 0x1BD11BDAu ^ k0 ^ k1;
  x0 += ks0; x1 += ks1;
#define TFR(r) { x0 += x1; x1 = rotl32(x1, r); x1 ^= x0; }
  TFR(13u) TFR(15u) TFR(26u) TFR(6u)   x0 += ks1; x1 += ks2 + 1u;
  TFR(17u) TFR(29u) TFR(16u) TFR(24u)  x0 += ks2; x1 += ks0 + 2u;
  TFR(13u) TFR(15u) TFR(26u) TFR(6u)   x0 += ks0; x1 += ks1 + 3u;
  TFR(17u) TFR(29u) TFR(16u) TFR(24u)  x0 += ks1; x1 += ks2 + 4u;
  TFR(13u) TFR(15u) TFR(26u) TFR(6u)   x0 += ks2; x1 += ks0 + 5u;
#undef TFR
  o0 = x0; o1 = x1;
}

__device__ __forceinline__ float bits_to_gumbel(uint32_t bits) {
  // jax.random.uniform(minval=tiny, maxval=1) then -log(-log(u))
  uint32_t v = (bits >> 9) | 0x3F800000u;
  float f = __uint_as_float(v) - 1.0f;
  if (f <= 0.0f) f = 1.17549435e-38f;
  return -logf(-logf(f));
}

__global__ void gumbel_kernel(float* __restrict__ g_read, float* __restrict__ g_ab) {
  uint32_t k1a, k1b, k2a, k2b;
#if TF_PARTITIONABLE
  threefry2x32(0u, 42u, 0u, 0u, k1a, k1b);
  threefry2x32(0u, 42u, 0u, 1u, k2a, k2b);
#else
  { uint32_t p0, p1, q0, q1;
    threefry2x32(0u, 42u, 0u, 2u, p0, p1);
    threefry2x32(0u, 42u, 1u, 3u, q0, q1);
    k1a = p0; k1b = q0; k2a = p1; k2b = q1; }
#endif
  const uint32_t NG = (uint32_t)LL * BB * NSLOT;  // 2097152
  const uint32_t NA = (uint32_t)LL * BB * 4;      // 16384
  uint32_t i = blockIdx.x * blockDim.x + threadIdx.x;
  if (i < NG) {
    uint32_t bits, o0, o1;
#if TF_PARTITIONABLE
    threefry2x32(k1a, k1b, 0u, i, o0, o1); bits = o0 ^ o1;
#else
    uint32_t H = NG / 2; uint32_t x0 = (i < H) ? i : i - H;
    threefry2x32(k1a, k1b, x0, x0 + H, o0, o1); bits = (i < H) ? o0 : o1;
#endif
    g_read[i] = bits_to_gumbel(bits);
  }
  if (i < NA) {
    uint32_t bits, o0, o1;
#if TF_PARTITIONABLE
    threefry2x32(k2a, k2b, 0u, i, o0, o1); bits = o0 ^ o1;
#else
    uint32_t H = NA / 2; uint32_t x0 = (i < H) ? i : i - H;
    threefry2x32(k2a, k2b, x0, x0 + H, o0, o1); bits = (i < H) ? o0 : o1;
#endif
    g_ab[i] = bits_to_gumbel(bits);
  }
}

// ------------------------------ weight packs -------------------------------
__global__ void pack_wcat(const float* __restrict__ Wh2c, const float* __restrict__ Wh2w,
                          const float* __restrict__ Wh2g, const float* __restrict__ Wh2ab,
                          const float* __restrict__ Wh2tau, float* __restrict__ Wcat) {
  int idx = blockIdx.x * blockDim.x + threadIdx.x;
  if (idx >= HDIM * WCOLS) return;
  int k = idx / WCOLS, c = idx % WCOLS;
  float v = 0.0f;
  if (c < 1024)       v = Wh2c[(size_t)k * HDIM + c];
  else if (c < 1280)  v = Wh2w[(size_t)k * AC + (c - 1024)];
  else if (c < 1283)  v = Wh2g[k * 3 + (c - 1280)];
  else if (c < 1285)  v = Wh2ab[k * 2 + (c - 1283)];
  else if (c == 1285) v = Wh2tau[k];
  Wcat[idx] = v;
}

__global__ void pack_wicat(const float* __restrict__ Wi2c, const float* __restrict__ Wi2w,
                           const float* __restrict__ Wi2g, const float* __restrict__ Wi2ab,
                           float* __restrict__ Wicat) {
  int idx = blockIdx.x * blockDim.x + threadIdx.x;
  if (idx >= IDIM * WCOLS) return;
  int k = idx / WCOLS, c = idx % WCOLS;
  float v = 0.0f;
  if (c < 1024)      v = Wi2c[(size_t)k * HDIM + c];
  else if (c < 1280) v = Wi2w[(size_t)k * AC + (c - 1024)];
  else if (c < 1283) v = Wi2g[k * 3 + (c - 1280)];
  else if (c < 1285) v = Wi2ab[k * 2 + (c - 1283)];
  Wicat[idx] = v;
}

// addrW[n][m] = sum_{k<A} mem_bias[n][k] * W_m2w[k][m]   (constant all steps)
__global__ void addrw_kernel(const float* __restrict__ mem_bias,
                             const float* __restrict__ Wm2w,
                             float* __restrict__ addrW) {
  int idx = blockIdx.x * blockDim.x + threadIdx.x;
  if (idx >= NSLOT * AC) return;
  int n = idx / AC, m = idx % AC;
  float acc = 0.0f;
  for (int k = 0; k < AA; k++) acc += mem_bias[(size_t)n * AC + k] * Wm2w[(size_t)k * AC + m];
  addrW[idx] = acc;
}

__global__ void init_kernel(const float* __restrict__ hid, float* __restrict__ h,
                            float* __restrict__ cc, float* __restrict__ w_sum,
                            int* __restrict__ lastWriter) {
  int idx = blockIdx.x * blockDim.x + threadIdx.x;
  if (idx < BB * HDIM) { h[idx] = hid[idx]; cc[idx] = 0.0f; }
  if (idx < BB * NSLOT) { w_sum[idx] = 0.0f; lastWriter[idx] = -1; }
}

// ------------------------------ generic fp32 GEMM --------------------------
template<int TM, int TN, int KC>
__global__ __launch_bounds__(256) void gemm_f32(const float* __restrict__ Amat,
                                                const float* __restrict__ Wmat,
                                                float* __restrict__ Cmat,
                                                int M, int K, int Nw) {
  constexpr int NRG = 256 / TN;
  constexpr int RT  = (TM * TN) / 256;
  __shared__ float shA[TM][KC + 1];
  int colT = threadIdx.x % TN;
  int rg   = threadIdx.x / TN;
  int m0   = blockIdx.x * TM;
  int col  = blockIdx.y * TN + colT;
  float acc[RT];
#pragma unroll
  for (int i = 0; i < RT; i++) acc[i] = 0.0f;
  for (int k0 = 0; k0 < K; k0 += KC) {
    for (int idx = threadIdx.x; idx < TM * KC; idx += 256) {
      int r = idx / KC, c = idx % KC;
      shA[r][c] = Amat[(size_t)(m0 + r) * K + k0 + c];
    }
    __syncthreads();
#pragma unroll 8
    for (int kk = 0; kk < KC; kk++) {
      float w = Wmat[(size_t)(k0 + kk) * Nw + col];
#pragma unroll
      for (int i = 0; i < RT; i++) acc[i] += shA[rg + i * NRG][kk] * w;
    }
    __syncthreads();
  }
#pragma unroll
  for (int i = 0; i < RT; i++)
    Cmat[(size_t)(m0 + rg + i * NRG) * Nw + col] = acc[i];
}

// ------------------------------ per-step kernels ---------------------------
// layernorm(w_sum) @ W_u2w  -> u2w (B x AC)
__global__ __launch_bounds__(256) void u2w_kernel(const float* __restrict__ w_sum,
                                                  const float* __restrict__ Wu2w,
                                                  float* __restrict__ u2w) {
  int b = blockIdx.x;
  __shared__ float us[NSLOT];
  __shared__ float red[4];
  float s = 0.0f;
  for (int n = threadIdx.x; n < NSLOT; n += 256) {
    float v = w_sum[(size_t)b * NSLOT + n];
    us[n] = v; s += v;
  }
  for (int off = 32; off; off >>= 1) s += __shfl_down(s, off, 64);
  int wv = threadIdx.x >> 6, ln = threadIdx.x & 63;
  __syncthreads();
  if (ln == 0) red[wv] = s;
  __syncthreads();
  float S = red[0] + red[1] + red[2] + red[3];
  float mu = S / (float)NSLOT;
  float d = 0.0f;
  for (int n = threadIdx.x; n < NSLOT; n += 256) {
    float t = us[n] - mu; d += t * t;
  }
  for (int off = 32; off; off >>= 1) d += __shfl_down(d, off, 64);
  __syncthreads();
  if (ln == 0) red[wv] = d;
  __syncthreads();
  float V = (red[0] + red[1] + red[2] + red[3]) / (float)NSLOT;
  float rs = 1.0f / sqrtf(V + 1e-5f);
  __syncthreads();
  for (int n = threadIdx.x; n < NSLOT; n += 256) us[n] = (us[n] - mu) * rs;
  __syncthreads();
  for (int m = threadIdx.x; m < AC; m += 256) {
    float acc = 0.0f;
    for (int n = 0; n < NSLOT; n++) acc += us[n] * Wu2w[(size_t)n * AC + m];
    u2w[(size_t)b * AC + m] = acc;
  }
}

// logits[b][n] = sum_k tanh(bias[b][k] + addrW[n][k] + delta[b][n][k]) * atten[k]
__global__ __launch_bounds__(256) void logits_kernel(
    const float* __restrict__ hcat, const float* __restrict__ icat,
    const float* __restrict__ u2w, const float* __restrict__ addrW,
    const int* __restrict__ lastWriter, const float* __restrict__ valWHist,
    const float* __restrict__ atten, float* __restrict__ logits, int t) {
  int b  = blockIdx.y;
  int n0 = blockIdx.x * 32;
  __shared__ float bias[AC];
  __shared__ float attb[AC];
  for (int m = threadIdx.x; m < AC; m += 256) {
    bias[m] = hcat[(size_t)b * WCOLS + COL_W0 + m] +
              icat[(size_t)(t * BB + b) * WCOLS + COL_W0 + m] +
              u2w[(size_t)b * AC + m];
    attb[m] = atten[m];
  }
  __syncthreads();
  int wave = threadIdx.x >> 6, lane = threadIdx.x & 63;
  for (int ni = wave; ni < 32; ni += 4) {
    int n = n0 + ni;
    int s = lastWriter[(size_t)b * NSLOT + n];
    float p = 0.0f;
    if (s >= 0) {
      const float* dw = valWHist + ((size_t)b * LL + s) * AC;
      for (int k = lane; k < AC; k += 64)
        p += tanhf(bias[k] + addrW[(size_t)n * AC + k] + dw[k]) * attb[k];
    } else {
      for (int k = lane; k < AC; k += 64)
        p += tanhf(bias[k] + addrW[(size_t)n * AC + k]) * attb[k];
    }
    for (int off = 32; off; off >>= 1) p += __shfl_down(p, off, 64);
    if (lane == 0) logits[(size_t)b * NSLOT + n] = p;
  }
}

// per-batch: argmax, w*, r gather, gates, alpha/beta
__global__ __launch_bounds__(512) void select_kernel(
    const float* __restrict__ logits, const float* __restrict__ g_read,
    const float* __restrict__ hcat, const float* __restrict__ icat,
    const float* __restrict__ b_h2tau, const float* __restrict__ mem_bias,
    const int* __restrict__ lastWriter, const float* __restrict__ valHist,
    const float* __restrict__ Wr2g, const float* __restrict__ Wr2ab,
    const float* __restrict__ g_ab,
    float* __restrict__ r, float* __restrict__ fio, float* __restrict__ abh,
    int* __restrict__ nstar, float* __restrict__ wstar, int t) {
  int b = blockIdx.x, tid = threadIdx.x;
  __shared__ float sv[NSLOT];
  __shared__ int   si[NSLOT];
  __shared__ float rs[AC];
  __shared__ float sred[8];
  __shared__ float stau;
  float z = logits[(size_t)b * NSLOT + tid] +
            g_read[((size_t)(t * BB + b)) * NSLOT + tid];
  sv[tid] = z; si[tid] = tid;
  __syncthreads();
  for (int off = 256; off; off >>= 1) {
    if (tid < off) {
      float a = sv[tid], c2 = sv[tid + off];
      int ia = si[tid], ic = si[tid + off];
      if (c2 > a || (c2 == a && ic < ia)) { sv[tid] = c2; si[tid] = ic; }
    }
    __syncthreads();
  }
  float zmax = sv[0];
  int ns = si[0];
  if (tid == 0) {
    float x = hcat[(size_t)b * WCOLS + COL_TAU] + b_h2tau[0];
    float sp = fmaxf(x, 0.0f) + log1pf(expf(-fabsf(x)));  // softplus
    stau = sp + 1.0f;
    nstar[b] = ns;
  }
  __syncthreads();
  float tau = stau;
  float e = expf((z - zmax) / tau);
  for (int off = 32; off; off >>= 1) e += __shfl_down(e, off, 64);
  int wv = tid >> 6, ln = tid & 63;
  if (ln == 0) sred[wv] = e;
  __syncthreads();
  float D = sred[0] + sred[1] + sred[2] + sred[3] +
            sred[4] + sred[5] + sred[6] + sred[7];
  float ystar = 1.0f / D;
  float ws = (1.0f - ystar) + ystar;  // matches hard - sg(y) + y at the argmax
  if (tid == 0) wstar[b] = ws;
  int sW = lastWriter[(size_t)b * NSLOT + ns];
  if (tid < AC) {
    float mv;
    if (tid < AA) mv = mem_bias[(size_t)ns * AC + tid];
    else mv = (sW >= 0) ? valHist[((size_t)b * LL + sW) * CC + (tid - AA)] : 0.0f;
    float rv = ws * mv;
    rs[tid] = rv;
    r[(size_t)b * AC + tid] = rv;
  }
  __syncthreads();
  if (tid < 3) {
    float acc = 0.0f;
    for (int k = 0; k < AC; k++) acc += rs[k] * Wr2g[k * 3 + tid];
    float x = hcat[(size_t)b * WCOLS + COL_G0 + tid] +
              icat[(size_t)(t * BB + b) * WCOLS + COL_G0 + tid] + acc;
    fio[b * 3 + tid] = 1.0f / (1.0f + expf(-x));
  } else if (tid < 5) {
    int j = tid - 3;
    float acc = 0.0f;
    for (int k = 0; k < AC; k++) acc += rs[k] * Wr2ab[k * 2 + j];
    float x = hcat[(size_t)b * WCOLS + COL_AB0 + j] +
              icat[(size_t)(t * BB + b) * WCOLS + COL_AB0 + j] + acc;
    float g1 = g_ab[((size_t)(t * BB + b) * 2 + j) * 2 + 0];
    float g2 = g_ab[((size_t)(t * BB + b) * 2 + j) * 2 + 1];
    abh[b * 2 + j] = (x + g1 - g2) > 0.0f ? 1.0f : 0.0f;  // hard ST sigmoid
  }
}

// c_tilde / cc / h / out
__global__ __launch_bounds__(256) void update_kernel(
    const float* __restrict__ hcat, const float* __restrict__ icat,
    const float* __restrict__ r, const float* __restrict__ Wr2c,
    const float* __restrict__ fio, const float* __restrict__ abh,
    float* __restrict__ cc, float* __restrict__ h, float* __restrict__ out, int t) {
  int b = blockIdx.x;
  int hc = blockIdx.y * 256 + threadIdx.x;
  __shared__ float rs[AC];
  for (int k = threadIdx.x; k < AC; k += 256) rs[k] = r[(size_t)b * AC + k];
  __syncthreads();
  float rc = 0.0f;
#pragma unroll 4
  for (int k = 0; k < AC; k++) rc += rs[k] * Wr2c[(size_t)k * HDIM + hc];
  float f = fio[b * 3 + 0], ii = fio[b * 3 + 1], o = fio[b * 3 + 2];
  float alpha = abh[b * 2 + 0], beta = abh[b * 2 + 1];
  float arg = beta * hcat[(size_t)b * WCOLS + hc] +
              icat[(size_t)(t * BB + b) * WCOLS + hc] + alpha * rc;
  float ct = tanhf(arg);
  size_t bi = (size_t)b * HDIM + hc;
  float ccn = f * cc[bi] + ii * ct;
  float hn = o * tanhf(ccn);
  cc[bi] = ccn; h[bi] = hn;
  out[((size_t)t * BB + b) * HDIM + hc] = hn;
}

// val = h @ W_h2m; valW = val @ W_m2w[A:]; memory bookkeeping
__global__ __launch_bounds__(256) void val_kernel(
    const float* __restrict__ h, const float* __restrict__ Wh2m,
    const float* __restrict__ Wm2w, const int* __restrict__ nstar,
    const float* __restrict__ wstar, float* __restrict__ valHist,
    float* __restrict__ valWHist, int* __restrict__ lastWriter,
    float* __restrict__ w_sum, int t) {
  int b = blockIdx.x;
  __shared__ float hs[HDIM];
  __shared__ float vs[CC];
  for (int k = threadIdx.x; k < HDIM; k += 256) hs[k] = h[(size_t)b * HDIM + k];
  __syncthreads();
  if (threadIdx.x < CC) {
    int c = threadIdx.x;
    float acc = 0.0f;
    for (int k = 0; k < HDIM; k++) acc += hs[k] * Wh2m[(size_t)k * CC + c];
    vs[c] = acc;
    valHist[((size_t)b * LL + t) * CC + c] = acc;
  }
  __syncthreads();
  {
    int m = threadIdx.x;  // AC == 256 == blockDim
    float acc = 0.0f;
    for (int k = 0; k < CC; k++) acc += vs[k] * Wm2w[(size_t)(AA + k) * AC + m];
    valWHist[((size_t)b * LL + t) * AC + m] = acc;
  }
  if (threadIdx.x == 0) {
    int ns = nstar[b];
    int pos = (t * LL < NSLOT) ? (t * LL) : ns;  // ts = arange(L)*L
    lastWriter[(size_t)b * NSLOT + pos] = t;
    w_sum[(size_t)b * NSLOT + ns] += wstar[b];
  }
}

// ------------------------------ host ---------------------------------------
extern "C" void kernel_launch(void* const* d_in, const int* in_sizes, int n_in,
                              void* d_out, int out_size, void* d_ws, size_t ws_size,
                              hipStream_t stream) {
  const float* inp      = (const float*)d_in[0];
  const float* hid      = (const float*)d_in[1];
  const float* mem_bias = (const float*)d_in[2];
  const float* W_h2w    = (const float*)d_in[3];
  const float* W_i2w    = (const float*)d_in[4];
  const float* W_m2w    = (const float*)d_in[5];
  const float* W_u2w    = (const float*)d_in[6];
  const float* W_h2g    = (const float*)d_in[7];
  const float* W_i2g    = (const float*)d_in[8];
  const float* W_r2g    = (const float*)d_in[9];
  const float* W_h2ab   = (const float*)d_in[10];
  const float* W_i2ab   = (const float*)d_in[11];
  const float* W_r2ab   = (const float*)d_in[12];
  const float* W_h2c    = (const float*)d_in[13];
  const float* W_i2c    = (const float*)d_in[14];
  const float* W_r2c    = (const float*)d_in[15];
  const float* atten    = (const float*)d_in[16];
  const float* W_h2tau  = (const float*)d_in[17];
  const float* b_h2tau  = (const float*)d_in[18];
  const float* W_h2m    = (const float*)d_in[19];
  float* out = (float*)d_out;

  char* base = (char*)d_ws;
  size_t off = 0;
  auto alloc = [&](size_t elems) -> void* {
    void* p = (void*)(base + off);
    off += ((elems * 4 + 255) / 256) * 256;
    return p;
  };
  float* g_read   = (float*)alloc((size_t)LL * BB * NSLOT);
  float* g_ab     = (float*)alloc((size_t)LL * BB * 4);
  float* icat     = (float*)alloc((size_t)LL * BB * WCOLS);
  float* Wicat    = (float*)alloc((size_t)IDIM * WCOLS);
  float* Wcat     = (float*)alloc((size_t)HDIM * WCOLS);
  float* addrW    = (float*)alloc((size_t)NSLOT * AC);
  float* hbuf     = (float*)alloc((size_t)BB * HDIM);
  float* ccbuf    = (float*)alloc((size_t)BB * HDIM);
  float* w_sum    = (float*)alloc((size_t)BB * NSLOT);
  float* u2w      = (float*)alloc((size_t)BB * AC);
  float* hcat     = (float*)alloc((size_t)BB * WCOLS);
  float* logits   = (float*)alloc((size_t)BB * NSLOT);
  float* rbuf     = (float*)alloc((size_t)BB * AC);
  float* fio      = (float*)alloc((size_t)BB * 3);
  float* abh      = (float*)alloc((size_t)BB * 2);
  float* wstar    = (float*)alloc((size_t)BB);
  float* valHist  = (float*)alloc((size_t)BB * LL * CC);
  float* valWHist = (float*)alloc((size_t)BB * LL * AC);
  int*   nstar    = (int*)alloc((size_t)BB);
  int*   lastWriter = (int*)alloc((size_t)BB * NSLOT);

  hipLaunchKernelGGL(gumbel_kernel, dim3((LL * BB * NSLOT + 255) / 256), dim3(256), 0, stream,
                     g_read, g_ab);
  hipLaunchKernelGGL(pack_wcat, dim3((HDIM * WCOLS + 255) / 256), dim3(256), 0, stream,
                     W_h2c, W_h2w, W_h2g, W_h2ab, W_h2tau, Wcat);
  hipLaunchKernelGGL(pack_wicat, dim3((IDIM * WCOLS + 255) / 256), dim3(256), 0, stream,
                     W_i2c, W_i2w, W_i2g, W_i2ab, Wicat);
  hipLaunchKernelGGL(addrw_kernel, dim3((NSLOT * AC + 255) / 256), dim3(256), 0, stream,
                     mem_bias, W_m2w, addrW);
  hipLaunchKernelGGL(init_kernel, dim3((BB * HDIM + 255) / 256), dim3(256), 0, stream,
                     hid, hbuf, ccbuf, w_sum, lastWriter);
  hipLaunchKernelGGL((gemm_f32<32, 32, 64>), dim3((LL * BB) / 32, WCOLS / 32), dim3(256), 0, stream,
                     inp, Wicat, icat, LL * BB, IDIM, WCOLS);

  for (int t = 0; t < LL; t++) {
    hipLaunchKernelGGL(u2w_kernel, dim3(BB), dim3(256), 0, stream, w_sum, W_u2w, u2w);
    hipLaunchKernelGGL((gemm_f32<16, 32, 64>), dim3(BB / 16, WCOLS / 32), dim3(256), 0, stream,
                       hbuf, Wcat, hcat, BB, HDIM, WCOLS);
    hipLaunchKernelGGL(logits_kernel, dim3(NSLOT / 32, BB), dim3(256), 0, stream,
                       hcat, icat, u2w, addrW, lastWriter, valWHist, atten, logits, t);
    hipLaunchKernelGGL(select_kernel, dim3(BB), dim3(512), 0, stream,
                       logits, g_read, hcat, icat, b_h2tau, mem_bias, lastWriter, valHist,
                       W_r2g, W_r2ab, g_ab, rbuf, fio, abh, nstar, wstar, t);
    hipLaunchKernelGGL(update_kernel, dim3(BB, HDIM / 256), dim3(256), 0, stream,
                       hcat, icat, rbuf, W_r2c, fio, abh, ccbuf, hbuf, out, t);
    hipLaunchKernelGGL(val_kernel, dim3(BB), dim3(256), 0, stream,
                       hbuf, W_h2m, W_m2w, nstar, wstar, valHist, valWHist, lastWriter, w_sum, t);
  }
}